// Round 1
// baseline (4234.020 us; speedup 1.0000x reference)
//
#include <hip/hip_runtime.h>
#include <math.h>

#define B_ 8
#define S_ 1024
#define D_ 1024
#define H_ 16
#define DK_ 64
#define EPS_ 1e-5f

// ---------------------------------------------------------------------------
// fp32 tiled GEMM: C[M,N] = A[M,K] @ W  (+ optional bias/relu/row-mask)
// LAY: 0 = W is row-major [K,N]; 1 = W is (H, D, DK) head layout
// EPI: 0 = none; 1 = +bias, relu, row-mask; 2 = +bias, row-mask
// tile 64x64, BK=16, 256 threads, 4x4 outputs/thread
// ---------------------------------------------------------------------------
template<int LAY, int EPI>
__global__ __launch_bounds__(256)
void gemm64(const float* __restrict__ A, const float* __restrict__ W,
            const float* __restrict__ bias, const int* __restrict__ lens,
            float* __restrict__ C, int M, int N, int K)
{
    __shared__ float As[16][68];   // [k][m], stride 68 -> (4k+m)%32 banks, <=2-way
    __shared__ float Bs[16][68];   // [k][n]
    const int tid = threadIdx.x;
    const int tx = tid & 15, ty = tid >> 4;
    const int bn = blockIdx.x * 64, bm = blockIdx.y * 64;

    float acc[4][4] = {};

    for (int k0 = 0; k0 < K; k0 += 16) {
        // A tile 64x16 -> As[k][m]
        {
            const int k = tid & 15;
            const int m0 = tid >> 4;
            #pragma unroll
            for (int i = 0; i < 4; i++) {
                const int m = m0 + i * 16;
                As[k][m] = A[(size_t)(bm + m) * K + k0 + k];
            }
        }
        // B tile 16x64 -> Bs[k][n]
        {
            const int n = tid & 63;
            const int kq = tid >> 6;
            #pragma unroll
            for (int i = 0; i < 4; i++) {
                const int k = kq + i * 4;
                float v;
                if (LAY == 0) {
                    v = W[(size_t)(k0 + k) * N + bn + n];
                } else {
                    const int nn = bn + n;
                    v = W[((size_t)(nn >> 6) << 16) + (size_t)(k0 + k) * 64 + (nn & 63)];
                }
                Bs[k][n] = v;
            }
        }
        __syncthreads();
        #pragma unroll
        for (int k = 0; k < 16; k++) {
            float a[4], b[4];
            #pragma unroll
            for (int i = 0; i < 4; i++) a[i] = As[k][ty * 4 + i];
            #pragma unroll
            for (int j = 0; j < 4; j++) b[j] = Bs[k][tx * 4 + j];
            #pragma unroll
            for (int i = 0; i < 4; i++)
                #pragma unroll
                for (int j = 0; j < 4; j++)
                    acc[i][j] = fmaf(a[i], b[j], acc[i][j]);
        }
        __syncthreads();
    }

    #pragma unroll
    for (int i = 0; i < 4; i++) {
        const int m = bm + ty * 4 + i;
        bool valid = true;
        if (EPI != 0) {
            const int s = m & (S_ - 1);
            const int b = m >> 10;
            valid = (s < lens[b]);
        }
        #pragma unroll
        for (int j = 0; j < 4; j++) {
            const int n = bn + tx * 4 + j;
            float v = acc[i][j];
            if (EPI != 0) {
                v += bias[n];
                if (EPI == 1) v = fmaxf(v, 0.f);
                if (!valid) v = 0.f;
            }
            C[(size_t)m * N + n] = v;
        }
    }
}

// ---------------------------------------------------------------------------
// Flash-style attention, fp32. One block = 64 queries of one (b,h).
// 4 waves; wave w owns query rows [16w,16w+16). Phase1: lane=key.
// Phase2: lane=dim. Online softmax (m,l per row, replicated across lanes).
// Q pre-scaled by 1/sqrt(DK). Key loop bounded by len (mask semantics).
// ---------------------------------------------------------------------------
__global__ __launch_bounds__(256)
void attn_kernel(const float* __restrict__ Q, const float* __restrict__ K,
                 const float* __restrict__ V, const int* __restrict__ lens,
                 float* __restrict__ Z)
{
    __shared__ float Qs[64][65];
    __shared__ float Ks[64][65];
    __shared__ float Ps[64][65];   // stored transposed: Ps[k][q]
    __shared__ float Vs[64][64];

    const int tid  = threadIdx.x;
    const int lane = tid & 63;
    const int w    = tid >> 6;                 // wave id 0..3
    const int qt   = blockIdx.x;               // query tile
    const int h    = blockIdx.y;
    const int b    = blockIdx.z;
    const int len  = lens[b];
    const int qbase = qt * 64;
    const size_t bhoff = ((size_t)b * S_) * D_ + (size_t)h * DK_;
    float* zout = Z + bhoff;

    if (qbase >= len) {  // whole tile masked -> write zeros (ws is poisoned)
        #pragma unroll
        for (int i = 0; i < 16; i++) {
            const int q = w * 16 + i;
            zout[(size_t)(qbase + q) * D_ + lane] = 0.f;
        }
        return;
    }

    // load Q tile, pre-scaled
    {
        const int d = tid & 63, r0 = tid >> 6;
        #pragma unroll
        for (int i = 0; i < 16; i++) {
            const int r = r0 + i * 4;
            Qs[r][d] = Q[bhoff + (size_t)(qbase + r) * D_ + d] * 0.125f;
        }
    }

    float m_i[16], l_i[16], o_i[16], al[16];
    #pragma unroll
    for (int i = 0; i < 16; i++) { m_i[i] = -INFINITY; l_i[i] = 0.f; o_i[i] = 0.f; }

    const int ntiles = (len + 63) >> 6;
    for (int t = 0; t < ntiles; t++) {
        const int k0 = t * 64;
        {
            const int d = tid & 63, r0 = tid >> 6;
            #pragma unroll
            for (int i = 0; i < 16; i++) {
                const int r = r0 + i * 4;
                const size_t gi = bhoff + (size_t)(k0 + r) * D_ + d;
                Ks[r][d] = K[gi];
                Vs[r][d] = V[gi];
            }
        }
        __syncthreads();

        const int  kg = k0 + lane;
        const bool kvalid = (kg < len);
        #pragma unroll
        for (int i = 0; i < 16; i++) {
            const int q = w * 16 + i;
            float s = 0.f;
            #pragma unroll
            for (int d = 0; d < 64; d++)
                s = fmaf(Qs[q][d], Ks[lane][d], s);
            s = kvalid ? s : -INFINITY;
            float mt = s;
            #pragma unroll
            for (int off = 32; off; off >>= 1) mt = fmaxf(mt, __shfl_xor(mt, off, 64));
            const float mn = fmaxf(m_i[i], mt);
            const float p  = __expf(s - mn);
            float rs = p;
            #pragma unroll
            for (int off = 32; off; off >>= 1) rs += __shfl_xor(rs, off, 64);
            al[i]  = __expf(m_i[i] - mn);
            m_i[i] = mn;
            l_i[i] = l_i[i] * al[i] + rs;
            Ps[lane][q] = p;   // transposed store: conflict-free, phase2 reads vectorize
        }
        __syncthreads();

        #pragma unroll
        for (int i = 0; i < 16; i++) o_i[i] *= al[i];
        for (int r = 0; r < 64; r++) {
            const float v = Vs[r][lane];
            #pragma unroll
            for (int i = 0; i < 16; i++)
                o_i[i] = fmaf(Ps[r][w * 16 + i], v, o_i[i]);
        }
        __syncthreads();
    }

    #pragma unroll
    for (int i = 0; i < 16; i++) {
        const int q = qbase + w * 16 + i;
        const float v = (q < len) ? o_i[i] / l_i[i] : 0.f;
        zout[(size_t)q * D_ + lane] = v;
    }
}

// ---------------------------------------------------------------------------
// Fused residual-add + LayerNorm over D=1024. One block (256 thr) per row.
// out = LN(X + Y) * w + b
// ---------------------------------------------------------------------------
__global__ __launch_bounds__(256)
void add_ln_kernel(const float* __restrict__ X, const float* __restrict__ Y,
                   const float* __restrict__ g, const float* __restrict__ beta,
                   float* __restrict__ out)
{
    const int row = blockIdx.x;
    const int tid = threadIdx.x;
    const float4 xv = ((const float4*)(X + (size_t)row * D_))[tid];
    const float4 yv = ((const float4*)(Y + (size_t)row * D_))[tid];
    float vx = xv.x + yv.x, vy = xv.y + yv.y, vz = xv.z + yv.z, vw = xv.w + yv.w;

    __shared__ float red[8];
    float s = vx + vy + vz + vw;
    #pragma unroll
    for (int off = 32; off; off >>= 1) s += __shfl_xor(s, off, 64);
    const int wv = tid >> 6, lane = tid & 63;
    if (lane == 0) red[wv] = s;
    __syncthreads();
    const float mean = (red[0] + red[1] + red[2] + red[3]) * (1.f / D_);

    const float dx = vx - mean, dy = vy - mean, dz = vz - mean, dw = vw - mean;
    float s2 = dx * dx + dy * dy + dz * dz + dw * dw;
    #pragma unroll
    for (int off = 32; off; off >>= 1) s2 += __shfl_xor(s2, off, 64);
    if (lane == 0) red[4 + wv] = s2;
    __syncthreads();
    const float var = (red[4] + red[5] + red[6] + red[7]) * (1.f / D_);
    const float rstd = rsqrtf(var + EPS_);

    const float4 gv = ((const float4*)g)[tid];
    const float4 bv = ((const float4*)beta)[tid];
    float4 o;
    o.x = dx * rstd * gv.x + bv.x;
    o.y = dy * rstd * gv.y + bv.y;
    o.z = dz * rstd * gv.z + bv.z;
    o.w = dw * rstd * gv.w + bv.w;
    ((float4*)(out + (size_t)row * D_))[tid] = o;
}

// ---------------------------------------------------------------------------
extern "C" void kernel_launch(void* const* d_in, const int* in_sizes, int n_in,
                              void* d_out, int out_size, void* d_ws, size_t ws_size,
                              hipStream_t stream)
{
    const float* x    = (const float*)d_in[0];
    const float* Wq   = (const float*)d_in[1];
    const float* Wk   = (const float*)d_in[2];
    const float* Wv   = (const float*)d_in[3];
    const float* fc1w = (const float*)d_in[4];
    const float* fc1b = (const float*)d_in[5];
    const float* fc2w = (const float*)d_in[6];
    const float* fc2b = (const float*)d_in[7];
    const float* ln1w = (const float*)d_in[8];
    const float* ln1b = (const float*)d_in[9];
    const float* ln2w = (const float*)d_in[10];
    const float* ln2b = (const float*)d_in[11];
    const int*   lens = (const int*)d_in[12];
    float* out = (float*)d_out;

    char* ws = (char*)d_ws;
    const size_t SZ = (size_t)B_ * S_ * D_ * sizeof(float);  // 32 MB
    float* Qb = (float*)(ws);
    float* Kb = (float*)(ws + SZ);
    float* Vb = (float*)(ws + 2 * SZ);
    float* Zb = (float*)(ws + 3 * SZ);
    float* X1 = Qb;   // Q dead after attention
    float* H1 = Kb;   // K dead after attention
    float* FF = Vb;   // V dead after attention

    const int M = B_ * S_;
    dim3 gg(D_ / 64, M / 64);

    // QKV projections: layout (B,S,D) with head h at cols [h*64, h*64+64)
    gemm64<1, 0><<<gg, 256, 0, stream>>>(x, Wq, nullptr, nullptr, Qb, M, D_, D_);
    gemm64<1, 0><<<gg, 256, 0, stream>>>(x, Wk, nullptr, nullptr, Kb, M, D_, D_);
    gemm64<1, 0><<<gg, 256, 0, stream>>>(x, Wv, nullptr, nullptr, Vb, M, D_, D_);

    attn_kernel<<<dim3(S_ / 64, H_, B_), 256, 0, stream>>>(Qb, Kb, Vb, lens, Zb);

    add_ln_kernel<<<M, 256, 0, stream>>>(x, Zb, ln1w, ln1b, X1);

    gemm64<0, 1><<<gg, 256, 0, stream>>>(X1, fc1w, fc1b, lens, H1, M, D_, D_);
    gemm64<0, 2><<<gg, 256, 0, stream>>>(H1, fc2w, fc2b, lens, FF, M, D_, D_);

    add_ln_kernel<<<M, 256, 0, stream>>>(X1, FF, ln2w, ln2b, out);
}

// Round 2
// 1425.652 us; speedup vs baseline: 2.9699x; 2.9699x over previous
//
#include <hip/hip_runtime.h>
#include <math.h>

#define B_ 8
#define S_ 1024
#define D_ 1024
#define H_ 16
#define DK_ 64
#define EPS_ 1e-5f

typedef __bf16 bf16_t;
typedef __bf16 bf16x8 __attribute__((ext_vector_type(8)));
typedef float  f32x4  __attribute__((ext_vector_type(4)));

// ---------------------------------------------------------------------------
// fp32 tiled GEMM: C[M,N] = A[M,K] @ W  (+ optional bias/relu/row-mask)
// LAY: 0 = W row-major [K,N]; 1 = W is (H, D, DK) head layout
// EPI: 0 = none; 1 = +bias, relu, row-mask; 2 = +bias, row-mask
// OUT: float or __bf16 output
// ---------------------------------------------------------------------------
template<int LAY, int EPI, typename OUT>
__global__ __launch_bounds__(256)
void gemm64(const float* __restrict__ A, const float* __restrict__ W,
            const float* __restrict__ bias, const int* __restrict__ lens,
            OUT* __restrict__ C, int M, int N, int K)
{
    __shared__ float As[16][68];
    __shared__ float Bs[16][68];
    const int tid = threadIdx.x;
    const int tx = tid & 15, ty = tid >> 4;
    const int bn = blockIdx.x * 64, bm = blockIdx.y * 64;

    float acc[4][4] = {};

    for (int k0 = 0; k0 < K; k0 += 16) {
        {
            const int k = tid & 15;
            const int m0 = tid >> 4;
            #pragma unroll
            for (int i = 0; i < 4; i++) {
                const int m = m0 + i * 16;
                As[k][m] = A[(size_t)(bm + m) * K + k0 + k];
            }
        }
        {
            const int n = tid & 63;
            const int kq = tid >> 6;
            #pragma unroll
            for (int i = 0; i < 4; i++) {
                const int k = kq + i * 4;
                float v;
                if (LAY == 0) {
                    v = W[(size_t)(k0 + k) * N + bn + n];
                } else {
                    const int nn = bn + n;
                    v = W[((size_t)(nn >> 6) << 16) + (size_t)(k0 + k) * 64 + (nn & 63)];
                }
                Bs[k][n] = v;
            }
        }
        __syncthreads();
        #pragma unroll
        for (int k = 0; k < 16; k++) {
            float a[4], b[4];
            #pragma unroll
            for (int i = 0; i < 4; i++) a[i] = As[k][ty * 4 + i];
            #pragma unroll
            for (int j = 0; j < 4; j++) b[j] = Bs[k][tx * 4 + j];
            #pragma unroll
            for (int i = 0; i < 4; i++)
                #pragma unroll
                for (int j = 0; j < 4; j++)
                    acc[i][j] = fmaf(a[i], b[j], acc[i][j]);
        }
        __syncthreads();
    }

    #pragma unroll
    for (int i = 0; i < 4; i++) {
        const int m = bm + ty * 4 + i;
        bool valid = true;
        if (EPI != 0) {
            const int s = m & (S_ - 1);
            const int b = m >> 10;
            valid = (s < lens[b]);
        }
        #pragma unroll
        for (int j = 0; j < 4; j++) {
            const int n = bn + tx * 4 + j;
            float v = acc[i][j];
            if (EPI != 0) {
                v += bias[n];
                if (EPI == 1) v = fmaxf(v, 0.f);
                if (!valid) v = 0.f;
            }
            C[(size_t)m * N + n] = (OUT)v;
        }
    }
}

// ---------------------------------------------------------------------------
// bf16 MFMA flash attention. One block = (b, h, 64-query tile), 4 waves.
// Wave w owns queries [16w, 16w+16). Per 64-key tile:
//   QK^T: 8x mfma_f32_16x16x32_bf16 -> S frags in C layout
//         (row = quad*4+reg, col = ntile*16 + (lane&15))  [m89-verified]
//   online softmax: row-reduce = butterfly over the 16 lanes of the quad
//   P: LDS round-trip (C layout -> A layout), bf16
//   PV: 8x mfma, V staged TRANSPOSED in LDS so B frags are ds_read_b128
// All bf16 LDS rows padded +8 (stride 72 = 144 B) -> 2-way conflicts (free).
// ---------------------------------------------------------------------------
__global__ __launch_bounds__(256)
void attn_mfma(const bf16_t* __restrict__ Q, const bf16_t* __restrict__ K,
               const bf16_t* __restrict__ V, const int* __restrict__ lens,
               float* __restrict__ Z)
{
    __shared__ __align__(16) bf16_t Qs[64][72];
    __shared__ __align__(16) bf16_t Ks[64][72];
    __shared__ __align__(16) bf16_t Vt[64][72];   // [d][key]
    __shared__ __align__(16) bf16_t Ps[64][72];   // [q][key]

    const int tid  = threadIdx.x;
    const int lane = tid & 63;
    const int w    = tid >> 6;
    const int quad = lane >> 4;
    const int l16  = lane & 15;
    const int qt   = blockIdx.x;
    const int h    = blockIdx.y;
    const int b    = blockIdx.z;
    const int len  = lens[b];
    const int qbase = qt * 64;
    const size_t bhoff = ((size_t)b * S_) * D_ + (size_t)h * DK_;  // element offset

    if (qbase >= len) {   // fully masked query tile -> zeros
        const int r = tid >> 2, c0 = (tid & 3) * 16;
        float* zp = Z + bhoff + (size_t)(qbase + r) * D_ + c0;
        #pragma unroll
        for (int i = 0; i < 4; i++)
            ((float4*)zp)[i] = make_float4(0.f, 0.f, 0.f, 0.f);
        return;
    }

    // stage Q tile (64 x 64 bf16): thread -> row tid>>2, 16 cols
    {
        const int r = tid >> 2, c0 = (tid & 3) * 16;
        const bf16_t* src = Q + bhoff + (size_t)(qbase + r) * D_ + c0;
        *(uint4*)&Qs[r][c0]     = *(const uint4*)src;
        *(uint4*)&Qs[r][c0 + 8] = *(const uint4*)(src + 8);
    }

    f32x4 o[4];
    float m_r[4], l_r[4];
    #pragma unroll
    for (int nt = 0; nt < 4; nt++)
        #pragma unroll
        for (int r = 0; r < 4; r++) o[nt][r] = 0.f;
    #pragma unroll
    for (int r = 0; r < 4; r++) { m_r[r] = -INFINITY; l_r[r] = 0.f; }

    const int ntiles = (len + 63) >> 6;
    for (int t = 0; t < ntiles; t++) {
        const int k0 = t * 64;
        // stage K (row-major) and V (transposed) tiles
        {
            const int r = tid >> 2, c0 = (tid & 3) * 16;
            const bf16_t* ksrc = K + bhoff + (size_t)(k0 + r) * D_ + c0;
            *(uint4*)&Ks[r][c0]     = *(const uint4*)ksrc;
            *(uint4*)&Ks[r][c0 + 8] = *(const uint4*)(ksrc + 8);
            const bf16_t* vsrc = V + bhoff + (size_t)(k0 + r) * D_ + c0;
            bf16x8 v0 = *(const bf16x8*)vsrc;
            bf16x8 v1 = *(const bf16x8*)(vsrc + 8);
            #pragma unroll
            for (int i = 0; i < 8; i++) Vt[c0 + i][r] = v0[i];
            #pragma unroll
            for (int i = 0; i < 8; i++) Vt[c0 + 8 + i][r] = v1[i];
        }
        __syncthreads();

        // ---- QK^T ----
        f32x4 sf[4];
        #pragma unroll
        for (int nt = 0; nt < 4; nt++)
            #pragma unroll
            for (int r = 0; r < 4; r++) sf[nt][r] = 0.f;
        bf16x8 aq0 = *(const bf16x8*)&Qs[w * 16 + l16][quad * 8];
        bf16x8 aq1 = *(const bf16x8*)&Qs[w * 16 + l16][32 + quad * 8];
        #pragma unroll
        for (int nt = 0; nt < 4; nt++) {
            bf16x8 b0 = *(const bf16x8*)&Ks[nt * 16 + l16][quad * 8];
            bf16x8 b1 = *(const bf16x8*)&Ks[nt * 16 + l16][32 + quad * 8];
            sf[nt] = __builtin_amdgcn_mfma_f32_16x16x32_bf16(aq0, b0, sf[nt], 0, 0, 0);
            sf[nt] = __builtin_amdgcn_mfma_f32_16x16x32_bf16(aq1, b1, sf[nt], 0, 0, 0);
        }

        // ---- scale, mask, online softmax ----
        float rowmax[4] = {-INFINITY, -INFINITY, -INFINITY, -INFINITY};
        #pragma unroll
        for (int nt = 0; nt < 4; nt++) {
            const bool kv = (k0 + nt * 16 + l16) < len;
            #pragma unroll
            for (int r = 0; r < 4; r++) {
                float s = kv ? sf[nt][r] * 0.125f : -INFINITY;
                sf[nt][r] = s;
                rowmax[r] = fmaxf(rowmax[r], s);
            }
        }
        #pragma unroll
        for (int r = 0; r < 4; r++) {
            float v = rowmax[r];
            v = fmaxf(v, __shfl_xor(v, 1));
            v = fmaxf(v, __shfl_xor(v, 2));
            v = fmaxf(v, __shfl_xor(v, 4));
            v = fmaxf(v, __shfl_xor(v, 8));
            rowmax[r] = v;
        }
        float alpha[4], rowsum[4];
        #pragma unroll
        for (int r = 0; r < 4; r++) {
            const float mn = fmaxf(m_r[r], rowmax[r]);
            alpha[r] = __expf(m_r[r] - mn);
            m_r[r] = mn;
            rowsum[r] = 0.f;
        }
        #pragma unroll
        for (int nt = 0; nt < 4; nt++) {
            #pragma unroll
            for (int r = 0; r < 4; r++) {
                const float p = __expf(sf[nt][r] - m_r[r]);
                rowsum[r] += p;
                Ps[w * 16 + quad * 4 + r][nt * 16 + l16] = (bf16_t)p;
            }
        }
        #pragma unroll
        for (int r = 0; r < 4; r++) {
            float v = rowsum[r];
            v += __shfl_xor(v, 1);
            v += __shfl_xor(v, 2);
            v += __shfl_xor(v, 4);
            v += __shfl_xor(v, 8);
            l_r[r] = l_r[r] * alpha[r] + v;
        }

        // ---- rescale O, then PV ----
        #pragma unroll
        for (int nt = 0; nt < 4; nt++)
            #pragma unroll
            for (int r = 0; r < 4; r++) o[nt][r] *= alpha[r];

        bf16x8 pa0 = *(const bf16x8*)&Ps[w * 16 + l16][quad * 8];
        bf16x8 pa1 = *(const bf16x8*)&Ps[w * 16 + l16][32 + quad * 8];
        #pragma unroll
        for (int nt = 0; nt < 4; nt++) {
            bf16x8 vb0 = *(const bf16x8*)&Vt[nt * 16 + l16][quad * 8];
            bf16x8 vb1 = *(const bf16x8*)&Vt[nt * 16 + l16][32 + quad * 8];
            o[nt] = __builtin_amdgcn_mfma_f32_16x16x32_bf16(pa0, vb0, o[nt], 0, 0, 0);
            o[nt] = __builtin_amdgcn_mfma_f32_16x16x32_bf16(pa1, vb1, o[nt], 0, 0, 0);
        }
        __syncthreads();
    }

    // ---- epilogue: /l, mask q>=len, store fp32 ----
    float inv[4];
    #pragma unroll
    for (int r = 0; r < 4; r++) inv[r] = 1.f / l_r[r];
    #pragma unroll
    for (int nt = 0; nt < 4; nt++) {
        #pragma unroll
        for (int r = 0; r < 4; r++) {
            const int q = qbase + w * 16 + quad * 4 + r;
            const float val = (q < len) ? o[nt][r] * inv[r] : 0.f;
            Z[bhoff + (size_t)q * D_ + nt * 16 + l16] = val;
        }
    }
}

// ---------------------------------------------------------------------------
// Fused residual-add + LayerNorm over D=1024. One block (256 thr) per row.
// ---------------------------------------------------------------------------
__global__ __launch_bounds__(256)
void add_ln_kernel(const float* __restrict__ X, const float* __restrict__ Y,
                   const float* __restrict__ g, const float* __restrict__ beta,
                   float* __restrict__ out)
{
    const int row = blockIdx.x;
    const int tid = threadIdx.x;
    const float4 xv = ((const float4*)(X + (size_t)row * D_))[tid];
    const float4 yv = ((const float4*)(Y + (size_t)row * D_))[tid];
    float vx = xv.x + yv.x, vy = xv.y + yv.y, vz = xv.z + yv.z, vw = xv.w + yv.w;

    __shared__ float red[8];
    float s = vx + vy + vz + vw;
    #pragma unroll
    for (int off = 32; off; off >>= 1) s += __shfl_xor(s, off, 64);
    const int wv = tid >> 6, lane = tid & 63;
    if (lane == 0) red[wv] = s;
    __syncthreads();
    const float mean = (red[0] + red[1] + red[2] + red[3]) * (1.f / D_);

    const float dx = vx - mean, dy = vy - mean, dz = vz - mean, dw = vw - mean;
    float s2 = dx * dx + dy * dy + dz * dz + dw * dw;
    #pragma unroll
    for (int off = 32; off; off >>= 1) s2 += __shfl_xor(s2, off, 64);
    if (lane == 0) red[4 + wv] = s2;
    __syncthreads();
    const float var = (red[4] + red[5] + red[6] + red[7]) * (1.f / D_);
    const float rstd = rsqrtf(var + EPS_);

    const float4 gv = ((const float4*)g)[tid];
    const float4 bv = ((const float4*)beta)[tid];
    float4 oo;
    oo.x = dx * rstd * gv.x + bv.x;
    oo.y = dy * rstd * gv.y + bv.y;
    oo.z = dz * rstd * gv.z + bv.z;
    oo.w = dw * rstd * gv.w + bv.w;
    ((float4*)(out + (size_t)row * D_))[tid] = oo;
}

// ---------------------------------------------------------------------------
extern "C" void kernel_launch(void* const* d_in, const int* in_sizes, int n_in,
                              void* d_out, int out_size, void* d_ws, size_t ws_size,
                              hipStream_t stream)
{
    const float* x    = (const float*)d_in[0];
    const float* Wq   = (const float*)d_in[1];
    const float* Wk   = (const float*)d_in[2];
    const float* Wv   = (const float*)d_in[3];
    const float* fc1w = (const float*)d_in[4];
    const float* fc1b = (const float*)d_in[5];
    const float* fc2w = (const float*)d_in[6];
    const float* fc2b = (const float*)d_in[7];
    const float* ln1w = (const float*)d_in[8];
    const float* ln1b = (const float*)d_in[9];
    const float* ln2w = (const float*)d_in[10];
    const float* ln2b = (const float*)d_in[11];
    const int*   lens = (const int*)d_in[12];
    float* out = (float*)d_out;

    char* ws = (char*)d_ws;
    const size_t SZ = (size_t)B_ * S_ * D_ * sizeof(float);  // 32 MB
    bf16_t* Qb = (bf16_t*)(ws);             // 16 MB used of 32 MB slot
    bf16_t* Kb = (bf16_t*)(ws + SZ);
    bf16_t* Vb = (bf16_t*)(ws + 2 * SZ);
    float*  Zb = (float*)(ws + 3 * SZ);
    float*  X1 = (float*)(ws);              // Q dead after attention
    float*  H1 = (float*)(ws + SZ);         // K dead after attention
    float*  FF = (float*)(ws + 2 * SZ);     // V dead after attention

    const int M = B_ * S_;
    dim3 gg(D_ / 64, M / 64);

    gemm64<1, 0, bf16_t><<<gg, 256, 0, stream>>>(x, Wq, nullptr, nullptr, Qb, M, D_, D_);
    gemm64<1, 0, bf16_t><<<gg, 256, 0, stream>>>(x, Wk, nullptr, nullptr, Kb, M, D_, D_);
    gemm64<1, 0, bf16_t><<<gg, 256, 0, stream>>>(x, Wv, nullptr, nullptr, Vb, M, D_, D_);

    attn_mfma<<<dim3(S_ / 64, H_, B_), 256, 0, stream>>>(Qb, Kb, Vb, lens, Zb);

    add_ln_kernel<<<M, 256, 0, stream>>>(x, Zb, ln1w, ln1b, X1);

    gemm64<0, 1, float><<<gg, 256, 0, stream>>>(X1, fc1w, fc1b, lens, H1, M, D_, D_);
    gemm64<0, 2, float><<<gg, 256, 0, stream>>>(H1, fc2w, fc2b, lens, FF, M, D_, D_);

    add_ln_kernel<<<M, 256, 0, stream>>>(X1, FF, ln2w, ln2b, out);
}

// Round 3
// 386.601 us; speedup vs baseline: 10.9519x; 3.6877x over previous
//
#include <hip/hip_runtime.h>
#include <math.h>

#define B_ 8
#define S_ 1024
#define D_ 1024
#define H_ 16
#define DK_ 64
#define EPS_ 1e-5f

typedef __bf16 bf16_t;
typedef __bf16 bf16x8 __attribute__((ext_vector_type(8)));
typedef __bf16 bf16x4v __attribute__((ext_vector_type(4)));
typedef float  f32x4  __attribute__((ext_vector_type(4)));

__device__ __forceinline__ void gld16(const void* g, void* l) {
    __builtin_amdgcn_global_load_lds(
        (const __attribute__((address_space(1))) void*)g,
        (__attribute__((address_space(3))) void*)l, 16, 0, 0);
}

// ---------------------------------------------------------------------------
// f32 -> bf16 elementwise convert (4 elems/thread)
// ---------------------------------------------------------------------------
__global__ __launch_bounds__(256)
void cvt_bf16(const float* __restrict__ src, bf16_t* __restrict__ dst)
{
    const int i = (blockIdx.x * 256 + threadIdx.x) * 4;
    const float4 v = *(const float4*)(src + i);
    bf16x4v o = { (bf16_t)v.x, (bf16_t)v.y, (bf16_t)v.z, (bf16_t)v.w };
    *(bf16x4v*)(dst + i) = o;
}

// ---------------------------------------------------------------------------
// Weight transpose + convert: all 5 weight matrices in one launch (z selects).
// z=0,1,2: Wq/Wk/Wv head layout (H,D,DK) -> WtQKV[n=z*1024+h*64+e][k=d]
// z=3,4:   fc1_w/fc2_w [K][N] -> Wt[n][k]
// 64x64 tile per block, fp32 LDS tile, bf16 transposed write.
// ---------------------------------------------------------------------------
__global__ __launch_bounds__(256)
void wtrans(const float* __restrict__ Wq, const float* __restrict__ Wk,
            const float* __restrict__ Wv, const float* __restrict__ W1,
            const float* __restrict__ W2, bf16_t* __restrict__ WtQKV,
            bf16_t* __restrict__ Wt1, bf16_t* __restrict__ Wt2)
{
    __shared__ float tile[64][65];
    const int tid = threadIdx.x;
    const int z = blockIdx.z;
    const int n0 = blockIdx.x * 64, k0 = blockIdx.y * 64;
    const int col = tid & 63, r0 = tid >> 6;

    const float* src = (z == 0) ? Wq : (z == 1) ? Wk : (z == 2) ? Wv
                     : (z == 3) ? W1 : W2;
    #pragma unroll
    for (int i = 0; i < 16; i++) {
        const int row = r0 + i * 4;  // k within tile
        float v;
        if (z < 3)  // head layout: h = n0>>6, element (d=k0+row, e=col)
            v = src[((size_t)(n0 >> 6) << 16) + (size_t)(k0 + row) * 64 + col];
        else
            v = src[(size_t)(k0 + row) * D_ + n0 + col];
        tile[row][col] = v;
    }
    __syncthreads();
    bf16_t* dst = (z < 3) ? (WtQKV + (size_t)z * D_ * D_)
                : (z == 3) ? Wt1 : Wt2;
    #pragma unroll
    for (int i = 0; i < 16; i++) {
        const int nr = r0 + i * 4;   // n within tile
        dst[(size_t)(n0 + nr) * D_ + k0 + col] = (bf16_t)tile[col][nr];
    }
}

// ---------------------------------------------------------------------------
// bf16 MFMA GEMM, m97 structure: 128x128 tile, BK=32, 256 thr (2x2 waves,
// each wave 4x4 frags of 16x16x32). A[M][K] bf16, Bw[N][K] bf16 (pre-transposed).
// Staging via global_load_lds width=16; chunk-XOR swizzle (c ^= (m^(m>>2))&3)
// applied on the GLOBAL source so frag ds_read_b128 are conflict-free.
// EPI: 0 = plain store; 1 = +bias,relu,row-mask; 2 = +bias,row-mask
// ---------------------------------------------------------------------------
template<int EPI, typename OUT>
__global__ __launch_bounds__(256)
void gemm_mfma(const bf16_t* __restrict__ A, const bf16_t* __restrict__ Bw,
               const float* __restrict__ bias, const int* __restrict__ lens,
               OUT* __restrict__ C, int M, int N, int K)
{
    __shared__ bf16_t As[128 * 32];
    __shared__ bf16_t Bs[128 * 32];
    const int tid  = threadIdx.x;
    const int lane = tid & 63;
    const int w    = tid >> 6;
    const int quad = lane >> 4, l16 = lane & 15;
    const int wm = w & 1, wn = w >> 1;
    const int bn = blockIdx.x * 128, bm = blockIdx.y * 128;

    f32x4 acc[4][4];
    #pragma unroll
    for (int i = 0; i < 4; i++)
        #pragma unroll
        for (int j = 0; j < 4; j++)
            #pragma unroll
            for (int r = 0; r < 4; r++) acc[i][j][r] = 0.f;

    const int fsw = (quad ^ (l16 ^ (l16 >> 2))) & 3;  // frag-read chunk col

    for (int k0 = 0; k0 < K; k0 += 32) {
        #pragma unroll
        for (int j = 0; j < 2; j++) {
            const int chunk = j * 256 + tid;
            const int m = chunk >> 2, cs = chunk & 3;
            const int cg = cs ^ ((m ^ (m >> 2)) & 3);
            gld16(A + (size_t)(bm + m) * K + k0 + cg * 8,
                  (char*)As + (size_t)(j * 256 + w * 64) * 16);
            gld16(Bw + (size_t)(bn + m) * K + k0 + cg * 8,
                  (char*)Bs + (size_t)(j * 256 + w * 64) * 16);
        }
        __syncthreads();

        bf16x8 a[4], b[4];
        #pragma unroll
        for (int i = 0; i < 4; i++)
            a[i] = *(const bf16x8*)&As[(wm * 64 + i * 16 + l16) * 32 + fsw * 8];
        #pragma unroll
        for (int j = 0; j < 4; j++)
            b[j] = *(const bf16x8*)&Bs[(wn * 64 + j * 16 + l16) * 32 + fsw * 8];
        #pragma unroll
        for (int i = 0; i < 4; i++)
            #pragma unroll
            for (int j = 0; j < 4; j++)
                acc[i][j] = __builtin_amdgcn_mfma_f32_16x16x32_bf16(a[i], b[j], acc[i][j], 0, 0, 0);
        __syncthreads();
    }

    // epilogue: C row = bm + wm*64 + i*16 + quad*4 + r, col = bn + wn*64 + j*16 + l16
    #pragma unroll
    for (int i = 0; i < 4; i++) {
        #pragma unroll
        for (int r = 0; r < 4; r++) {
            const int m = bm + wm * 64 + i * 16 + quad * 4 + r;
            float keep = 1.f;
            if (EPI != 0) {
                const int s = m & (S_ - 1);
                const int bb = m >> 10;
                keep = (s < lens[bb]) ? 1.f : 0.f;
            }
            #pragma unroll
            for (int j = 0; j < 4; j++) {
                const int n = bn + wn * 64 + j * 16 + l16;
                float v = acc[i][j][r];
                if (EPI != 0) {
                    v += bias[n];
                    if (EPI == 1) v = fmaxf(v, 0.f);
                    v *= keep;
                }
                C[(size_t)m * N + n] = (OUT)v;
            }
        }
    }
}

// ---------------------------------------------------------------------------
// bf16 MFMA flash attention on packed QKV [8192][3072] (Q|K|V each 1024 cols,
// head h at col h*64). One block = (b,h,64-query tile), 4 waves.
// ---------------------------------------------------------------------------
__global__ __launch_bounds__(256)
void attn_mfma(const bf16_t* __restrict__ QKV, const int* __restrict__ lens,
               float* __restrict__ Z)
{
    __shared__ __align__(16) bf16_t Qs[64][72];
    __shared__ __align__(16) bf16_t Ks[64][72];
    __shared__ __align__(16) bf16_t Vt[64][72];   // [d][key]
    __shared__ __align__(16) bf16_t Ps[64][72];   // [q][key]

    const int tid  = threadIdx.x;
    const int lane = tid & 63;
    const int w    = tid >> 6;
    const int quad = lane >> 4;
    const int l16  = lane & 15;
    const int qt   = blockIdx.x;
    const int h    = blockIdx.y;
    const int b    = blockIdx.z;
    const int len  = lens[b];
    const int qbase = qt * 64;
    const size_t qkvbase = (size_t)b * S_ * 3072 + (size_t)h * 64;
    const size_t zbase   = (size_t)b * S_ * D_  + (size_t)h * 64;

    if (qbase >= len) {
        const int r = tid >> 2, c0 = (tid & 3) * 16;
        float* zp = Z + zbase + (size_t)(qbase + r) * D_ + c0;
        #pragma unroll
        for (int i = 0; i < 4; i++)
            ((float4*)zp)[i] = make_float4(0.f, 0.f, 0.f, 0.f);
        return;
    }

    {
        const int r = tid >> 2, c0 = (tid & 3) * 16;
        const bf16_t* src = QKV + qkvbase + (size_t)(qbase + r) * 3072 + c0;
        *(uint4*)&Qs[r][c0]     = *(const uint4*)src;
        *(uint4*)&Qs[r][c0 + 8] = *(const uint4*)(src + 8);
    }

    f32x4 o[4];
    float m_r[4], l_r[4];
    #pragma unroll
    for (int nt = 0; nt < 4; nt++)
        #pragma unroll
        for (int r = 0; r < 4; r++) o[nt][r] = 0.f;
    #pragma unroll
    for (int r = 0; r < 4; r++) { m_r[r] = -INFINITY; l_r[r] = 0.f; }

    const int ntiles = (len + 63) >> 6;
    for (int t = 0; t < ntiles; t++) {
        const int k0 = t * 64;
        {
            const int r = tid >> 2, c0 = (tid & 3) * 16;
            const bf16_t* ksrc = QKV + qkvbase + 1024 + (size_t)(k0 + r) * 3072 + c0;
            *(uint4*)&Ks[r][c0]     = *(const uint4*)ksrc;
            *(uint4*)&Ks[r][c0 + 8] = *(const uint4*)(ksrc + 8);
            const bf16_t* vsrc = QKV + qkvbase + 2048 + (size_t)(k0 + r) * 3072 + c0;
            bf16x8 v0 = *(const bf16x8*)vsrc;
            bf16x8 v1 = *(const bf16x8*)(vsrc + 8);
            #pragma unroll
            for (int i = 0; i < 8; i++) Vt[c0 + i][r] = v0[i];
            #pragma unroll
            for (int i = 0; i < 8; i++) Vt[c0 + 8 + i][r] = v1[i];
        }
        __syncthreads();

        f32x4 sf[4];
        #pragma unroll
        for (int nt = 0; nt < 4; nt++)
            #pragma unroll
            for (int r = 0; r < 4; r++) sf[nt][r] = 0.f;
        bf16x8 aq0 = *(const bf16x8*)&Qs[w * 16 + l16][quad * 8];
        bf16x8 aq1 = *(const bf16x8*)&Qs[w * 16 + l16][32 + quad * 8];
        #pragma unroll
        for (int nt = 0; nt < 4; nt++) {
            bf16x8 b0 = *(const bf16x8*)&Ks[nt * 16 + l16][quad * 8];
            bf16x8 b1 = *(const bf16x8*)&Ks[nt * 16 + l16][32 + quad * 8];
            sf[nt] = __builtin_amdgcn_mfma_f32_16x16x32_bf16(aq0, b0, sf[nt], 0, 0, 0);
            sf[nt] = __builtin_amdgcn_mfma_f32_16x16x32_bf16(aq1, b1, sf[nt], 0, 0, 0);
        }

        float rowmax[4] = {-INFINITY, -INFINITY, -INFINITY, -INFINITY};
        #pragma unroll
        for (int nt = 0; nt < 4; nt++) {
            const bool kv = (k0 + nt * 16 + l16) < len;
            #pragma unroll
            for (int r = 0; r < 4; r++) {
                float s = kv ? sf[nt][r] * 0.125f : -INFINITY;
                sf[nt][r] = s;
                rowmax[r] = fmaxf(rowmax[r], s);
            }
        }
        #pragma unroll
        for (int r = 0; r < 4; r++) {
            float v = rowmax[r];
            v = fmaxf(v, __shfl_xor(v, 1));
            v = fmaxf(v, __shfl_xor(v, 2));
            v = fmaxf(v, __shfl_xor(v, 4));
            v = fmaxf(v, __shfl_xor(v, 8));
            rowmax[r] = v;
        }
        float alpha[4], rowsum[4];
        #pragma unroll
        for (int r = 0; r < 4; r++) {
            const float mn = fmaxf(m_r[r], rowmax[r]);
            alpha[r] = __expf(m_r[r] - mn);
            m_r[r] = mn;
            rowsum[r] = 0.f;
        }
        #pragma unroll
        for (int nt = 0; nt < 4; nt++) {
            #pragma unroll
            for (int r = 0; r < 4; r++) {
                const float p = __expf(sf[nt][r] - m_r[r]);
                rowsum[r] += p;
                Ps[w * 16 + quad * 4 + r][nt * 16 + l16] = (bf16_t)p;
            }
        }
        #pragma unroll
        for (int r = 0; r < 4; r++) {
            float v = rowsum[r];
            v += __shfl_xor(v, 1);
            v += __shfl_xor(v, 2);
            v += __shfl_xor(v, 4);
            v += __shfl_xor(v, 8);
            l_r[r] = l_r[r] * alpha[r] + v;
        }

        #pragma unroll
        for (int nt = 0; nt < 4; nt++)
            #pragma unroll
            for (int r = 0; r < 4; r++) o[nt][r] *= alpha[r];

        bf16x8 pa0 = *(const bf16x8*)&Ps[w * 16 + l16][quad * 8];
        bf16x8 pa1 = *(const bf16x8*)&Ps[w * 16 + l16][32 + quad * 8];
        #pragma unroll
        for (int nt = 0; nt < 4; nt++) {
            bf16x8 vb0 = *(const bf16x8*)&Vt[nt * 16 + l16][quad * 8];
            bf16x8 vb1 = *(const bf16x8*)&Vt[nt * 16 + l16][32 + quad * 8];
            o[nt] = __builtin_amdgcn_mfma_f32_16x16x32_bf16(pa0, vb0, o[nt], 0, 0, 0);
            o[nt] = __builtin_amdgcn_mfma_f32_16x16x32_bf16(pa1, vb1, o[nt], 0, 0, 0);
        }
        __syncthreads();
    }

    float inv[4];
    #pragma unroll
    for (int r = 0; r < 4; r++) inv[r] = 1.f / l_r[r];
    #pragma unroll
    for (int nt = 0; nt < 4; nt++) {
        #pragma unroll
        for (int r = 0; r < 4; r++) {
            const int q = qbase + w * 16 + quad * 4 + r;
            const float val = (q < len) ? o[nt][r] * inv[r] : 0.f;
            Z[zbase + (size_t)q * D_ + nt * 16 + l16] = val;
        }
    }
}

// ---------------------------------------------------------------------------
// Residual-add + LayerNorm, D=1024, one block per row.
// LN1: X fp32 + Y fp32 -> bf16 out.  LN2: X bf16 + Y fp32 -> fp32 out.
// ---------------------------------------------------------------------------
__device__ __forceinline__ void ln_core(float vx, float vy, float vz, float vw,
                                        int tid, float& mean, float& rstd)
{
    __shared__ float red[8];
    float s = vx + vy + vz + vw;
    #pragma unroll
    for (int off = 32; off; off >>= 1) s += __shfl_xor(s, off, 64);
    const int wv = tid >> 6, lane = tid & 63;
    if (lane == 0) red[wv] = s;
    __syncthreads();
    mean = (red[0] + red[1] + red[2] + red[3]) * (1.f / D_);
    const float dx = vx - mean, dy = vy - mean, dz = vz - mean, dw = vw - mean;
    float s2 = dx * dx + dy * dy + dz * dz + dw * dw;
    #pragma unroll
    for (int off = 32; off; off >>= 1) s2 += __shfl_xor(s2, off, 64);
    if (lane == 0) red[4 + wv] = s2;
    __syncthreads();
    rstd = rsqrtf((red[4] + red[5] + red[6] + red[7]) * (1.f / D_) + EPS_);
}

__global__ __launch_bounds__(256)
void add_ln1(const float* __restrict__ X, const float* __restrict__ Y,
             const float* __restrict__ g, const float* __restrict__ beta,
             bf16_t* __restrict__ out)
{
    const int row = blockIdx.x, tid = threadIdx.x;
    const float4 xv = ((const float4*)(X + (size_t)row * D_))[tid];
    const float4 yv = ((const float4*)(Y + (size_t)row * D_))[tid];
    const float vx = xv.x + yv.x, vy = xv.y + yv.y, vz = xv.z + yv.z, vw = xv.w + yv.w;
    float mean, rstd;
    ln_core(vx, vy, vz, vw, tid, mean, rstd);
    const float4 gv = ((const float4*)g)[tid];
    const float4 bv = ((const float4*)beta)[tid];
    bf16x4v o;
    o[0] = (bf16_t)((vx - mean) * rstd * gv.x + bv.x);
    o[1] = (bf16_t)((vy - mean) * rstd * gv.y + bv.y);
    o[2] = (bf16_t)((vz - mean) * rstd * gv.z + bv.z);
    o[3] = (bf16_t)((vw - mean) * rstd * gv.w + bv.w);
    *(bf16x4v*)(out + (size_t)row * D_ + tid * 4) = o;
}

__global__ __launch_bounds__(256)
void add_ln2(const bf16_t* __restrict__ X, const float* __restrict__ Y,
             const float* __restrict__ g, const float* __restrict__ beta,
             float* __restrict__ out)
{
    const int row = blockIdx.x, tid = threadIdx.x;
    const bf16x4v xv = *(const bf16x4v*)(X + (size_t)row * D_ + tid * 4);
    const float4 yv = ((const float4*)(Y + (size_t)row * D_))[tid];
    const float vx = (float)xv[0] + yv.x, vy = (float)xv[1] + yv.y;
    const float vz = (float)xv[2] + yv.z, vw = (float)xv[3] + yv.w;
    float mean, rstd;
    ln_core(vx, vy, vz, vw, tid, mean, rstd);
    const float4 gv = ((const float4*)g)[tid];
    const float4 bv = ((const float4*)beta)[tid];
    float4 o;
    o.x = (vx - mean) * rstd * gv.x + bv.x;
    o.y = (vy - mean) * rstd * gv.y + bv.y;
    o.z = (vz - mean) * rstd * gv.z + bv.z;
    o.w = (vw - mean) * rstd * gv.w + bv.w;
    ((float4*)(out + (size_t)row * D_))[tid] = o;
}

// ---------------------------------------------------------------------------
extern "C" void kernel_launch(void* const* d_in, const int* in_sizes, int n_in,
                              void* d_out, int out_size, void* d_ws, size_t ws_size,
                              hipStream_t stream)
{
    const float* x    = (const float*)d_in[0];
    const float* Wq   = (const float*)d_in[1];
    const float* Wk   = (const float*)d_in[2];
    const float* Wv   = (const float*)d_in[3];
    const float* fc1w = (const float*)d_in[4];
    const float* fc1b = (const float*)d_in[5];
    const float* fc2w = (const float*)d_in[6];
    const float* fc2b = (const float*)d_in[7];
    const float* ln1w = (const float*)d_in[8];
    const float* ln1b = (const float*)d_in[9];
    const float* ln2w = (const float*)d_in[10];
    const float* ln2b = (const float*)d_in[11];
    const int*   lens = (const int*)d_in[12];
    float* out = (float*)d_out;

    char* ws = (char*)d_ws;
    const size_t MB = 1024 * 1024;
    bf16_t* QKVb  = (bf16_t*)(ws);              // 48 MB: [8192][3072]
    float*  Zb    = (float*)(ws + 48 * MB);     // 32 MB: [8192][1024]
    bf16_t* X1b   = (bf16_t*)(ws + 80 * MB);    // 16 MB
    bf16_t* xb    = (bf16_t*)(ws + 96 * MB);    // 16 MB (dead after QKV)
    bf16_t* H1b   = (bf16_t*)(ws + 96 * MB);    //   reuses xb slot
    float*  FF    = (float*)(ws + 48 * MB);     //   reuses Zb slot
    bf16_t* WtQKV = (bf16_t*)(ws + 112 * MB);   // 6 MB: [3072][1024]
    bf16_t* Wt1   = (bf16_t*)(ws + 118 * MB);   // 2 MB: [1024][1024]
    bf16_t* Wt2   = (bf16_t*)(ws + 120 * MB);   // 2 MB
    // total 122 MB

    const int M = B_ * S_;

    cvt_bf16<<<M * D_ / 1024, 256, 0, stream>>>(x, xb);
    wtrans<<<dim3(16, 16, 5), 256, 0, stream>>>(Wq, Wk, Wv, fc1w, fc2w, WtQKV, Wt1, Wt2);

    gemm_mfma<0, bf16_t><<<dim3(3072 / 128, M / 128), 256, 0, stream>>>(
        xb, WtQKV, nullptr, nullptr, QKVb, M, 3072, D_);

    attn_mfma<<<dim3(S_ / 64, H_, B_), 256, 0, stream>>>(QKVb, lens, Zb);

    add_ln1<<<M, 256, 0, stream>>>(x, Zb, ln1w, ln1b, X1b);

    gemm_mfma<1, bf16_t><<<dim3(D_ / 128, M / 128), 256, 0, stream>>>(
        X1b, Wt1, fc1b, lens, H1b, M, D_, D_);
    gemm_mfma<2, float><<<dim3(D_ / 128, M / 128), 256, 0, stream>>>(
        H1b, Wt2, fc2b, lens, FF, M, D_, D_);

    add_ln2<<<M, 256, 0, stream>>>(X1b, FF, ln2w, ln2b, out);
}